// Round 1
// 83.632 us; speedup vs baseline: 1.1264x; 1.1264x over previous
//
#include <hip/hip_runtime.h>
#include <math.h>

// Problem constants (from reference)
#define NB    16
#define NH    76
#define NW    76
#define NCELL (NH * NW)      // 5776
#define NITEM (NB * NCELL)   // 92416
#define NCH   32             // 19 + NC
#define NKP   9
#define NCLS  13
#define NT    50
#define NLROW 21             // 2*NK + 3
#define BLOCK 128
#define GRID  (NITEM / BLOCK)  // 722 -- exact cover, 1 item/thread, no guard needed

// 1/(exp(2)-1)
#define INV_EM1 0.15651764274966565f
#define SX 8.421052631578947f   // 640/76
#define SY 6.315789473684211f   // 480/76

__device__ __forceinline__ float sigmoidf_(float x) {
    return 1.0f / (1.0f + __expf(-x));
}

// R4 restructure. Measured context: dur_us(94.2) = ~86us of harness 256MiB
// poison fills (top-5 dispatches are all fillBufferAligned @41-43us; loss_main
// absent => <41us, modeled ~8us). This round attacks the ~8us:
//  - target rows staged once/block into LDS, pre-scaled to pixels, fixed trip
//    count via ballot-computed nvalid -> zero VMEM + no dependent break in t-loop
//  - wave-uniform d^2<80^2 early-reject skips ~70% of sqrt+exp (gt corners are
//    uniform over the image; only ~6.5% of corner evals are inside the gate)
//  - native v_sqrt_f32 (tolerance ~202; IEEE fixup sequence not needed)
//  - reduction: per-block partial -> plain store to d_ws slot (poison 0xAA is
//    overwritten), 1-block second kernel writes d_out[0] exactly. Replaces 512
//    same-address device atomics (~7ns each serialized, per R3's measurement).
//  - BLOCK=128 x GRID=722: 3-round/CU balance (~6% makespan waste vs 42% at
//    361x256 blocks)
__global__ __launch_bounds__(BLOCK) void loss_main(
    const float* __restrict__ out,   // (NB, 32, 76, 76)
    const float* __restrict__ dt,    // (NB, 32, 76, 76)
    const float* __restrict__ tgt,   // (NB, 1050)
    float* __restrict__ outp,        // scalar loss (fallback path only)
    float* __restrict__ partials,    // d_ws: one slot per block
    int use_ws)
{
    // A block spans <=2 batch values (b-boundary every 5776 cells); stage both.
    __shared__ float2 s_g[2][NT][NKP];   // gt corners pre-scaled to pixels
    __shared__ int    s_gij[2][NT];      // (gj<<8)|gi
    __shared__ int    s_cls[2][NT];
    __shared__ int    s_nv[2];           // cumprod-validity count
    __shared__ float  swsum[BLOCK / 64];

    const int tid  = threadIdx.x;
    const int idx0 = blockIdx.x * BLOCK;
    const int b0   = idx0 / NCELL;
    const int b1   = (idx0 + BLOCK - 1) / NCELL;   // b0 or b0+1

    // Stage 100 rows (2 b-values x 50 t), one row per thread.
    for (int u = tid; u < 2 * NT; u += BLOCK) {
        const int bi = u / NT;
        const int t  = u - bi * NT;
        const int bb = bi ? b1 : b0;
        const float* __restrict__ r = tgt + (size_t)bb * (NT * NLROW) + t * NLROW;
        #pragma unroll
        for (int k = 0; k < NKP; k++)
            s_g[bi][t][k] = make_float2(r[1 + 2 * k] * 640.0f, r[2 + 2 * k] * 480.0f);
        const int gi = (int)(r[1] * (float)NW);
        const int gj = (int)(r[2] * (float)NH);
        s_gij[bi][t] = (gj << 8) | gi;
        s_cls[bi][t] = min(max((int)r[0], 0), NCLS - 1);
    }
    // nvalid per b via ballot: wave w handles bi=w (BLOCK=128 -> exactly 2 waves).
    {
        const int wv = tid >> 6, ln = tid & 63;
        const int bb = wv ? b1 : b0;
        const float x0 = (ln < NT) ? tgt[(size_t)bb * (NT * NLROW) + ln * NLROW + 1] : 0.0f;
        const unsigned long long zmask = __ballot(x0 == 0.0f);  // lanes>=NT forced set
        if (ln == 0) s_nv[wv] = (int)__ffsll((unsigned long long)zmask) - 1;
    }
    __syncthreads();

    const int idx  = idx0 + tid;          // always < NITEM (exact grid)
    const int b    = idx / NCELL;
    const int cell = idx - b * NCELL;
    const int j    = cell / NW;
    const int i    = cell - j * NW;
    const int bi   = (b != b0);
    const int myg  = (j << 8) | i;
    const int nv   = s_nv[bi];
    const float fi = (float)i, fj = (float)j;

    const float* __restrict__ ob = out + (size_t)b * NCH * NCELL + cell;
    const float* __restrict__ db = dt  + (size_t)b * NCH * NCELL + cell;

    // Predicted corners: keep raw transformed channel values (ax/ay) for the
    // coord loss, and pixel-space positions (px/py) for the conf search.
    float ax[NKP], ay[NKP], px[NKP], py[NKP];
    #pragma unroll
    for (int k = 0; k < NKP; k++) {
        float cx = ob[(2 * k)     * NCELL];
        float cy = ob[(2 * k + 1) * NCELL];
        if (k == 0) { cx = sigmoidf_(cx); cy = sigmoidf_(cy); }
        ax[k] = cx; ay[k] = cy;
        px[k] = (cx + fi) * SX;
        py[k] = (cy + fj) * SY;
    }
    const float conf  = sigmoidf_(ob[18 * NCELL]);
    const float tconf = sigmoidf_(db[18 * NCELL]);

    float cur9 = 0.0f;                    // 9 * cur; compare vs 9*SIL = 5.4
    int flag = 0, tcls = 0;
    for (int t = 0; t < nv; t++) {
        const int g = s_gij[bi][t];
        if (g == myg) { flag = 1; tcls = s_cls[bi][t]; }   // last valid t wins
        float s = 0.0f;
        #pragma unroll
        for (int k = 0; k < NKP; k++) {
            const float2 gp = s_g[bi][t][k];
            const float dx = gp.x - px[k];
            const float dy = gp.y - py[k];
            const float d2 = __builtin_fmaf(dx, dx, dy * dy);
            // Wave-uniform reject: sqrt+exp only if some lane is inside 80px.
            if (__any(d2 < 6400.0f)) {
                const float dist = __builtin_amdgcn_sqrtf(d2);
                const float c = (__expf(__builtin_fmaf(dist, -0.025f, 2.0f)) - 1.0f) * INV_EM1;
                s += (d2 < 6400.0f) ? c : 0.0f;
            }
        }
        cur9 = fmaxf(cur9, s);
    }

    float total;
    {
        const float cmask = flag ? 5.0f : (cur9 > 5.4f ? 0.0f : 1.0f);
        const float dcf = conf - tconf;
        total = 0.5f * dcf * dcf * cmask;
    }

    if (flag) {   // rare (<=20 cells of 5776 per batch)
        float cl = 0.0f;
        #pragma unroll
        for (int k = 0; k < NKP; k++) {
            float bx = db[(2 * k)     * NCELL];
            float by = db[(2 * k + 1) * NCELL];
            if (k == 0) { bx = sigmoidf_(bx); by = sigmoidf_(by); }
            const float d1 = ax[k] - bx;
            const float d2_ = ay[k] - by;
            cl += d1 * d1 + d2_ * d2_;
        }
        total += 0.5f * cl;

        // log-softmax CE; track cv[tcls] via select so the array keeps
        // compile-time indices only (runtime index -> scratch, rule #20).
        float cvv[NCLS];
        float mx = -1e30f, vt = 0.0f;
        #pragma unroll
        for (int c2 = 0; c2 < NCLS; c2++) {
            const float v = ob[(19 + c2) * NCELL];
            cvv[c2] = v;
            mx = fmaxf(mx, v);
            vt = (c2 == tcls) ? v : vt;
        }
        float se = 0.0f;
        #pragma unroll
        for (int c2 = 0; c2 < NCLS; c2++) se += __expf(cvv[c2] - mx);
        total += mx + __logf(se) - vt;
    }

    // Wave butterfly -> cross-wave LDS -> ONE plain store per block (no atomics)
    #pragma unroll
    for (int off = 32; off > 0; off >>= 1)
        total += __shfl_down(total, off, 64);
    if ((tid & 63) == 0) swsum[tid >> 6] = total;
    __syncthreads();
    if (tid == 0) {
        float sm = swsum[0];
        #pragma unroll
        for (int w = 1; w < BLOCK / 64; w++) sm += swsum[w];
        if (use_ws) partials[blockIdx.x] = sm;   // overwrites 0xAA poison
        else        atomicAdd(outp, sm);         // fallback (poison -3e-13, ok)
    }
}

__global__ __launch_bounds__(256) void reduce_partials(
    const float* __restrict__ p, float* __restrict__ outp)
{
    __shared__ float w[4];
    float s = 0.0f;
    for (int k = threadIdx.x; k < GRID; k += 256) s += p[k];
    #pragma unroll
    for (int off = 32; off > 0; off >>= 1)
        s += __shfl_down(s, off, 64);
    if ((threadIdx.x & 63) == 0) w[threadIdx.x >> 6] = s;
    __syncthreads();
    if (threadIdx.x == 0) outp[0] = w[0] + w[1] + w[2] + w[3];  // exact overwrite
}

extern "C" void kernel_launch(void* const* d_in, const int* in_sizes, int n_in,
                              void* d_out, int out_size, void* d_ws, size_t ws_size,
                              hipStream_t stream) {
    const float* out_p = (const float*)d_in[0];   // output
    const float* dt_p  = (const float*)d_in[1];   // distiled_target
    const float* tgt_p = (const float*)d_in[2];   // target
    const int use_ws = (d_ws != nullptr && ws_size >= GRID * sizeof(float));
    float* partials = (float*)d_ws;

    loss_main<<<GRID, BLOCK, 0, stream>>>(out_p, dt_p, tgt_p, (float*)d_out,
                                          partials, use_ws);
    if (use_ws)
        reduce_partials<<<1, 256, 0, stream>>>(partials, (float*)d_out);
}